// Round 7
// baseline (198.155 us; speedup 1.0000x reference)
//
#include <hip/hip_runtime.h>
#include <hip/hip_bf16.h>

// Input: x [1, 512, 256, 256] f32, contiguous. Channel c = contiguous 65536 floats.
// Out: top-10 channel indices by mean (descending), int32.
//
// R3 lesson: single-counter device-scope atomic join costs ~60ns/block serialized
//            (4096 blocks = +225us). Two launches.
// R6 lesson: single-wave topk == tree topk (tail already negligible). Remaining
//            controllable share ~60us is the sum kernel; tune grid per G11.

#define C 512
#define HW 65536                 // 256*256
#define K_TOP 10
#define SEGS 4                   // segments (blocks) per channel
#define SEG_FLOATS (HW / SEGS)   // 16384 floats per segment
#define NBLOCKS (C * SEGS)       // 2048 = 8 blocks/CU * 256 CUs

// 2048 blocks x 256 threads: each block sums one contiguous 16384-float
// segment = 16 float4/thread, done as two unroll-8 passes (caps live VGPRs
// so 8 waves/SIMD stays eligible; 32 waves/CU = max occupancy).
__global__ __launch_bounds__(256) void partial_sum_kernel(
    const float* __restrict__ x, float* __restrict__ partials) {
    const int b = blockIdx.x;              // 0..2047
    const int c = b >> 2;
    const int seg = b & 3;
    const float4* p = reinterpret_cast<const float4*>(
        x + (size_t)c * HW + (size_t)seg * SEG_FLOATS);
    const int tid = threadIdx.x;

    float s = 0.f;
#pragma unroll
    for (int i = 0; i < 8; ++i) {          // first 8 float4 per thread
        float4 v = p[tid + i * 256];
        s += (v.x + v.y) + (v.z + v.w);
    }
#pragma unroll
    for (int i = 8; i < 16; ++i) {         // second 8 float4 per thread
        float4 v = p[tid + i * 256];
        s += (v.x + v.y) + (v.z + v.w);
    }

    // wave-64 shuffle reduction (no barrier inside a wave)
#pragma unroll
    for (int off = 32; off > 0; off >>= 1) s += __shfl_down(s, off, 64);

    __shared__ float ps[4];
    if ((tid & 63) == 0) ps[tid >> 6] = s;
    __syncthreads();
    if (tid == 0) partials[b] = (ps[0] + ps[1]) + (ps[2] + ps[3]);
}

// Single wave, zero barriers, zero LDS. Each lane owns 8 channels
// (ch = lane + 64*j); a channel's 4 partials are one float4.
// 10 rounds of {local argmax over 8, 64-lane butterfly argmax}.
__global__ __launch_bounds__(64) void topk_kernel(
    const float* __restrict__ partials, int* __restrict__ out) {
    const int lane = threadIdx.x;

    float lv[8];
    int   li[8];
#pragma unroll
    for (int j = 0; j < 8; ++j) {
        const int ch = lane + 64 * j;
        li[j] = ch;
        float4 a = reinterpret_cast<const float4*>(partials)[ch];
        lv[j] = (a.x + a.y) + (a.z + a.w);
    }

    for (int k = 0; k < K_TOP; ++k) {
        // local argmax over this lane's 8 (tie -> lower index)
        float bv = lv[0]; int bi = li[0];
#pragma unroll
        for (int j = 1; j < 8; ++j)
            if (lv[j] > bv || (lv[j] == bv && li[j] < bi)) { bv = lv[j]; bi = li[j]; }
        // 64-lane butterfly argmax — all lanes converge to the same winner
#pragma unroll
        for (int m = 1; m < 64; m <<= 1) {
            float ov = __shfl_xor(bv, m, 64);
            int   oi = __shfl_xor(bi, m, 64);
            if (ov > bv || (ov == bv && oi < bi)) { bv = ov; bi = oi; }
        }
        if (lane == 0) out[k] = bi;
        // owning lane removes the winner
#pragma unroll
        for (int j = 0; j < 8; ++j)
            if (li[j] == bi) lv[j] = -__builtin_inff();
    }
}

extern "C" void kernel_launch(void* const* d_in, const int* in_sizes, int n_in,
                              void* d_out, int out_size, void* d_ws, size_t ws_size,
                              hipStream_t stream) {
    const float* x = (const float*)d_in[0];
    int* out = (int*)d_out;
    float* partials = (float*)d_ws;        // C*SEGS = 2048 floats of scratch

    partial_sum_kernel<<<NBLOCKS, 256, 0, stream>>>(x, partials);
    topk_kernel<<<1, 64, 0, stream>>>(partials, out);
}

// Round 9
// 193.076 us; speedup vs baseline: 1.0263x; 1.0263x over previous
//
#include <hip/hip_runtime.h>
#include <hip/hip_bf16.h>

// Input: x [1, 512, 256, 256] f32, contiguous. Channel c = contiguous 65536 floats.
// Out: top-10 channel indices by mean (descending), int32.
//
// R3 lesson: 4096 same-address device-scope atomics serialize (~61ns each; +225us).
// R7 lesson: grid retunes of the sum kernel are noise (193-198us band).
// R8 lesson: hipLaunchCooperativeKernel does not execute under the harness's
//            graph capture (output stayed zeroed) -> two plain launches.

#define C 512
#define HW 65536                 // 256*256
#define K_TOP 10
#define SEGS 8                   // segments per channel
#define SEG_FLOATS (HW / SEGS)   // 8192 floats per segment
#define NBLOCKS (C * SEGS)       // 4096

// Grid: 4096 blocks x 256 threads. Each block sums one 8192-float contiguous
// segment (8 float4/thread), fully coalesced.
__global__ __launch_bounds__(256) void partial_sum_kernel(
    const float* __restrict__ x, float* __restrict__ partials) {
    const int b = blockIdx.x;              // 0..4095
    const int c = b >> 3;
    const int seg = b & 7;
    const float4* p = reinterpret_cast<const float4*>(
        x + (size_t)c * HW + (size_t)seg * SEG_FLOATS);
    const int tid = threadIdx.x;

    float s = 0.f;
#pragma unroll
    for (int i = 0; i < 8; ++i) {          // 8 * 256 threads * 4 floats = 8192
        float4 v = p[tid + i * 256];
        s += (v.x + v.y) + (v.z + v.w);
    }

    // wave-64 shuffle reduction (no barrier inside a wave)
#pragma unroll
    for (int off = 32; off > 0; off >>= 1) s += __shfl_down(s, off, 64);

    __shared__ float ps[4];
    if ((tid & 63) == 0) ps[tid >> 6] = s;
    __syncthreads();
    if (tid == 0) partials[b] = (ps[0] + ps[1]) + (ps[2] + ps[3]);
}

// Single wave, zero barriers, zero LDS. Each lane owns 8 channels
// (ch = lane + 64*j); a channel's 8 partials are contiguous -> two float4
// loads. 10 rounds of {local argmax over 8, 64-lane butterfly argmax}.
__global__ __launch_bounds__(64) void topk_kernel(
    const float* __restrict__ partials, int* __restrict__ out) {
    const int lane = threadIdx.x;

    float lv[8];
    int   li[8];
#pragma unroll
    for (int j = 0; j < 8; ++j) {
        const int ch = lane + 64 * j;
        li[j] = ch;
        const float4* p = reinterpret_cast<const float4*>(partials + ch * SEGS);
        float4 a = p[0], b = p[1];
        lv[j] = ((a.x + a.y) + (a.z + a.w)) + ((b.x + b.y) + (b.z + b.w));
    }

    for (int k = 0; k < K_TOP; ++k) {
        // local argmax over this lane's 8 (tie -> lower index)
        float bv = lv[0]; int bi = li[0];
#pragma unroll
        for (int j = 1; j < 8; ++j)
            if (lv[j] > bv || (lv[j] == bv && li[j] < bi)) { bv = lv[j]; bi = li[j]; }
        // 64-lane butterfly argmax — all lanes converge to the same winner
#pragma unroll
        for (int m = 1; m < 64; m <<= 1) {
            float ov = __shfl_xor(bv, m, 64);
            int   oi = __shfl_xor(bi, m, 64);
            if (ov > bv || (ov == bv && oi < bi)) { bv = ov; bi = oi; }
        }
        if (lane == 0) out[k] = bi;
        // owning lane removes the winner
#pragma unroll
        for (int j = 0; j < 8; ++j)
            if (li[j] == bi) lv[j] = -__builtin_inff();
    }
}

extern "C" void kernel_launch(void* const* d_in, const int* in_sizes, int n_in,
                              void* d_out, int out_size, void* d_ws, size_t ws_size,
                              hipStream_t stream) {
    const float* x = (const float*)d_in[0];
    int* out = (int*)d_out;
    float* partials = (float*)d_ws;        // 4096 floats of scratch

    partial_sum_kernel<<<NBLOCKS, 256, 0, stream>>>(x, partials);
    topk_kernel<<<1, 64, 0, stream>>>(partials, out);
}